// Round 9
// baseline (66.141 us; speedup 1.0000x reference)
//
#include <hip/hip_runtime.h>

#define H 128
#define NPOS 10
#define ROWSB 32
#define BLOCK 512

using bf16x8 = __attribute__((ext_vector_type(8))) short;
using f32x4  = __attribute__((ext_vector_type(4))) float;

__device__ __forceinline__ unsigned short f2bf(float f) {
  unsigned u = __float_as_uint(f);
  u += 0x7FFFu + ((u >> 16) & 1u);   // round-to-nearest-even
  return (unsigned short)(u >> 16);
}

__device__ __forceinline__ float sigm(float x) {
  return __builtin_amdgcn_rcpf(1.0f + __builtin_amdgcn_exp2f(-1.44269504f * x));
}
__device__ __forceinline__ float tanh_f(float x) {
  return 2.0f * __builtin_amdgcn_rcpf(1.0f + __builtin_amdgcn_exp2f(-2.88539008f * x)) - 1.0f;
}

// K1: weights prep + per-block pos histogram (NO global atomics, no memset needed).
// blocks [0,160): W_f transpose; [160,2080): W_iou copy; [2080,2080+nhb): histogram.
__global__ void prep_wt(const float* __restrict__ Wf, const float* __restrict__ Wiou,
                        unsigned short* __restrict__ wt,
                        const int* __restrict__ posp, int* __restrict__ hist2,
                        int N, int nhb) {
  int b = blockIdx.x, t = threadIdx.x;
  if (b < NPOS * 16) {
    __shared__ float tile[32][33];
    int p = b >> 4, jt = (b >> 2) & 3, kt = b & 3;
    int tx = t & 31, ty = t >> 5;            // 32 x 8
    #pragma unroll
    for (int it = 0; it < 4; ++it) {
      int krow = kt * 32 + ty + it * 8;
      int j = jt * 32 + tx;
      tile[ty + it * 8][tx] = Wf[(size_t)(p * H + krow) * H + j];
    }
    __syncthreads();
    #pragma unroll
    for (int it = 0; it < 4; ++it) {
      int j2 = jt * 32 + ty + it * 8;
      int k2 = kt * 32 + tx;
      wt[(size_t)p * 512 * H + (size_t)j2 * H + k2] = f2bf(tile[tx][ty + it * 8]);
    }
  } else if (b < NPOS * 16 + (NPOS * 384 * H) / 256) {
    int id = (b - NPOS * 16) * 256 + t;
    int p = id / 49152;
    int r = id - p * 49152;
    int k = r & 127;
    float v = Wiou[(size_t)(r >> 7) * (NPOS * H) + p * H + k];
    wt[(size_t)p * 65536 + 16384 + r] = f2bf(v);
  } else {
    int hb = b - (NPOS * 16 + (NPOS * 384 * H) / 256);
    __shared__ int c[NPOS];
    if (t < NPOS) c[t] = 0;
    __syncthreads();
    int i = hb * 256 + t;
    if (t < 256 && i < N) atomicAdd(&c[posp[i]], 1);   // LDS atomic only
    __syncthreads();
    if (t < NPOS) hist2[hb * 16 + t] = c[t];
  }
}

// K2: scans. off2[b][p] = global scatter base for hist-block b, pos p.
// Also builds the main-kernel block table.
__global__ void scan_build(const int* __restrict__ hist2, int nhb,
                           int* __restrict__ off2,
                           int* __restrict__ blkpos, int* __restrict__ blkgs,
                           int* __restrict__ blkcnt, int maxb) {
  __shared__ int tot[NPOS], base[NPOS + 1], bb[NPOS + 1];
  int t = threadIdx.x;
  if (t < NPOS) {
    int run = 0;
    for (int b = 0; b < nhb; ++b) { off2[b * 16 + t] = run; run += hist2[b * 16 + t]; }
    tot[t] = run;
  }
  __syncthreads();
  if (t == 0) {
    int run = 0, rb = 0;
    for (int p = 0; p < NPOS; ++p) {
      base[p] = run; bb[p] = rb;
      run += tot[p];
      rb += (tot[p] + ROWSB - 1) / ROWSB;
    }
    base[NPOS] = run; bb[NPOS] = rb;
  }
  __syncthreads();
  for (int i = t; i < nhb * NPOS; i += 256) {
    int b = i / NPOS, p = i - b * NPOS;
    off2[b * 16 + p] += base[p];
  }
  int nb = bb[NPOS];
  for (int b = t; b < maxb; b += 256) {
    if (b < nb) {
      int p = 0;
      while (bb[p + 1] <= b) ++p;
      int s = (b - bb[p]) * ROWSB;
      blkpos[b] = p;
      blkgs[b] = base[p] + s;
      blkcnt[b] = min(ROWSB, tot[p] - s);
    } else {
      blkpos[b] = -1;
    }
  }
}

// K3: scatter, global-atomic-free. LDS rank + precomputed per-(block,pos) base.
// order entry packs: g (bits 0..15) | mask<<16 | (depth==1)<<17 | (depth==2)<<18
__global__ void scatter_idx(const int* __restrict__ posp, const int* __restrict__ depthp,
                            const int* __restrict__ maskp, const int* __restrict__ off2,
                            unsigned* __restrict__ order, int N) {
  __shared__ int c[NPOS], basearr[NPOS];
  int hb = blockIdx.x, t = threadIdx.x;
  if (t < NPOS) { c[t] = 0; basearr[t] = off2[hb * 16 + t]; }
  __syncthreads();
  int i = hb * 256 + t;
  int p = -1, r = 0;
  unsigned e = 0;
  if (i < N) {
    p = posp[i];
    r = atomicAdd(&c[p], 1);                 // LDS atomic only
    int d = depthp[i];
    int mk = maskp[i];
    e = (unsigned)i | ((unsigned)mk << 16) |
        ((unsigned)(d == 1) << 17) | ((unsigned)(d == 2) << 18);
  }
  __syncthreads();
  if (p >= 0) order[basearr[p] + r] = e;
}

__global__ __launch_bounds__(BLOCK, 4) void tree_lstm_main(
    const float* __restrict__ child_h, const float* __restrict__ child_c,
    const float* __restrict__ e1, const float* __restrict__ e2,
    const float* __restrict__ h_prev,
    const float* __restrict__ b_f, const float* __restrict__ b_iou,
    const unsigned short* __restrict__ wt,
    const unsigned* __restrict__ order, const int* __restrict__ blkpos,
    const int* __restrict__ blkgs, const int* __restrict__ blkcnt,
    float* __restrict__ out, int N) {

  const int b = blockIdx.x;
  const int p = blkpos[b];
  if (p < 0) return;
  const int gs = blkgs[b], cnth = blkcnt[b];

  __shared__ unsigned short hs[ROWSB * H];   // 8 KB, XOR-swizzled bf16 h_cat
  __shared__ unsigned rowg[ROWSB];

  const int t = threadIdx.x;
  const int wv = t >> 6, l = t & 63;
  const int l15 = l & 15, lhi = l >> 4;
  const int colr = wv * 16 + l15;            // wave's output column 0..127
  const int kof = lhi * 8;

  const unsigned short* wb0 = wt + (size_t)p * 512 * H + (size_t)colr * H + kof;

  if (t < ROWSB) rowg[t] = (t < cnth) ? order[gs + t] : 0xFFFFFFFFu;
  __syncthreads();

  // ---- stage A: 32 rows x 128 bf16 (child_h + depth-class extras), 1 iter ----
  {
    int id = t;
    int row = id >> 4, c8 = id & 15;
    unsigned e = rowg[row];
    float4 a0 = {0.f, 0.f, 0.f, 0.f}, a1 = {0.f, 0.f, 0.f, 0.f};
    if ((int)e >= 0) {
      int g = e & 0xFFFF;
      const float4* ph = (const float4*)(child_h + (size_t)g * H + c8 * 8);
      a0 = ph[0]; a1 = ph[1];
      if (e & (3u << 17)) {
        const float* ep = (e & (1u << 17)) ? e1 : e2;
        const float4* pe = (const float4*)(ep + (size_t)g * H + c8 * 8);
        float4 b0 = pe[0], b1 = pe[1];
        a0.x += b0.x; a0.y += b0.y; a0.z += b0.z; a0.w += b0.w;
        a1.x += b1.x; a1.y += b1.y; a1.z += b1.z; a1.w += b1.w;
      }
    }
    bf16x8 v;
    v[0] = (short)f2bf(a0.x); v[1] = (short)f2bf(a0.y);
    v[2] = (short)f2bf(a0.z); v[3] = (short)f2bf(a0.w);
    v[4] = (short)f2bf(a1.x); v[5] = (short)f2bf(a1.y);
    v[6] = (short)f2bf(a1.z); v[7] = (short)f2bf(a1.w);
    int wb = (row * 256 + c8 * 16) ^ ((row & 7) << 4);
    *(bf16x8*)((char*)hs + wb) = v;
  }
  __syncthreads();

  const size_t NH = (size_t)N * H;
  const float bfv = b_f[p * H + colr];
  const float b_i = b_iou[colr], b_o = b_iou[H + colr], b_g = b_iou[2 * H + colr];

  const int nchunk = (cnth + 15) >> 4;
  for (int c = 0; c < nchunk; ++c) {
    const int r0 = c * 16;

    // A fragments: row = r0 + (l&15), k = kk*32 + (l>>4)*8 + j
    const int arow = r0 + l15;
    bf16x8 afr[4];
    #pragma unroll
    for (int kk = 0; kk < 4; ++kk) {
      int rb = (arow * 256 + kk * 64 + lhi * 16) ^ ((arow & 7) << 4);
      afr[kk] = *(const bf16x8*)((const char*)hs + rb);
    }

    // hoisted epilogue gathers — issue BEFORE MFMA so they overlap matrix work
    unsigned gg[4]; float cc[4], hpv[4];
    #pragma unroll
    for (int q = 0; q < 4; ++q) {
      int rr = r0 + lhi * 4 + q;
      gg[q] = (rr < cnth) ? rowg[rr] : 0xFFFFFFFFu;
    }
    #pragma unroll
    for (int q = 0; q < 4; ++q) {
      if ((int)gg[q] >= 0) {
        size_t gi = (size_t)(gg[q] & 0xFFFF) * H + colr;
        cc[q] = child_c[gi];
        hpv[q] = h_prev[gi];
      } else { cc[q] = 0.f; hpv[q] = 0.f; }
    }

    f32x4 au = {0.f, 0.f, 0.f, 0.f};
    f32x4 ai = {0.f, 0.f, 0.f, 0.f};
    f32x4 ao = {0.f, 0.f, 0.f, 0.f};
    f32x4 ag = {0.f, 0.f, 0.f, 0.f};
    #pragma unroll
    for (int kk = 0; kk < 4; ++kk) {
      bf16x8 bu = *(const bf16x8*)(wb0 + kk * 32);
      bf16x8 bi = *(const bf16x8*)(wb0 + 128 * H + kk * 32);
      bf16x8 bo = *(const bf16x8*)(wb0 + 256 * H + kk * 32);
      bf16x8 bg = *(const bf16x8*)(wb0 + 384 * H + kk * 32);
      au = __builtin_amdgcn_mfma_f32_16x16x32_bf16(afr[kk], bu, au, 0, 0, 0);
      ai = __builtin_amdgcn_mfma_f32_16x16x32_bf16(afr[kk], bi, ai, 0, 0, 0);
      ao = __builtin_amdgcn_mfma_f32_16x16x32_bf16(afr[kk], bo, ao, 0, 0, 0);
      ag = __builtin_amdgcn_mfma_f32_16x16x32_bf16(afr[kk], bg, ag, 0, 0, 0);
    }

    // epilogue: D row = (l>>4)*4 + q, col = l&15 (verified mapping)
    #pragma unroll
    for (int q = 0; q < 4; ++q) {
      if ((int)gg[q] >= 0) {
        size_t gi = (size_t)(gg[q] & 0xFFFF) * H + colr;
        float u = au[q] + bfv;
        float iv = ai[q] + b_i;
        float ov = ao[q] + b_o;
        float gv = ag[q] + b_g;
        float f = sigm(u);
        float credv = f * cc[q];
        float cnew = sigm(iv) * tanh_f(gv) + credv;
        float hnew = sigm(ov) * tanh_f(cnew);
        float m = (float)((gg[q] >> 16) & 1u);
        float hv = hpv[q] * m + (1.0f - m) * hnew;
        float cv = credv * m + (1.0f - m) * cnew;
        out[gi] = hv;
        out[NH + gi] = cv;
      }
    }
  }
}

extern "C" void kernel_launch(void* const* d_in, const int* in_sizes, int n_in,
                              void* d_out, int out_size, void* d_ws, size_t ws_size,
                              hipStream_t stream) {
  const float* child_h = (const float*)d_in[0];
  const float* child_c = (const float*)d_in[1];
  const float* e1      = (const float*)d_in[2];
  const float* e2      = (const float*)d_in[3];
  const float* h_prev  = (const float*)d_in[4];
  const int*   posp    = (const int*)d_in[5];
  const int*   depthp  = (const int*)d_in[6];
  const int*   maskp   = (const int*)d_in[7];
  const float* W_f     = (const float*)d_in[8];
  const float* b_f     = (const float*)d_in[9];
  const float* W_iou   = (const float*)d_in[10];
  const float* b_iou   = (const float*)d_in[11];
  float* out = (float*)d_out;
  int N = in_sizes[0] / H;
  int nhb = (N + 255) / 256;                 // histogram/scatter blocks
  int maxb = NPOS + N / ROWSB;

  // ws layout
  unsigned short* wt = (unsigned short*)d_ws;          // 655360 * 2B
  int* hist2  = (int*)((char*)d_ws + (size_t)NPOS * 512 * H * 2);  // nhb*16
  int* off2   = hist2 + nhb * 16;                                   // nhb*16
  int* blkpos = off2 + nhb * 16;
  int* blkgs  = blkpos + maxb;
  int* blkcnt = blkgs + maxb;
  unsigned* order = (unsigned*)(blkcnt + maxb);

  int prep_blocks = NPOS * 16 + (NPOS * 384 * H) / 256 + nhb;
  hipLaunchKernelGGL(prep_wt, dim3(prep_blocks), dim3(256), 0, stream,
                     W_f, W_iou, wt, posp, hist2, N, nhb);
  hipLaunchKernelGGL(scan_build, dim3(1), dim3(256), 0, stream,
                     hist2, nhb, off2, blkpos, blkgs, blkcnt, maxb);
  hipLaunchKernelGGL(scatter_idx, dim3(nhb), dim3(256), 0, stream,
                     posp, depthp, maskp, off2, order, N);
  hipLaunchKernelGGL(tree_lstm_main, dim3(maxb), dim3(BLOCK), 0, stream,
                     child_h, child_c, e1, e2, h_prev,
                     b_f, b_iou, wt, order, blkpos, blkgs, blkcnt, out, N);
}

// Round 10
// 49.973 us; speedup vs baseline: 1.3235x; 1.3235x over previous
//
#include <hip/hip_runtime.h>

#define H 128
#define NPOS 10
#define ROWSB 32
#define BLOCK 512

using bf16x8 = __attribute__((ext_vector_type(8))) short;
using f32x4  = __attribute__((ext_vector_type(4))) float;

__device__ __forceinline__ unsigned short f2bf(float f) {
  unsigned u = __float_as_uint(f);
  u += 0x7FFFu + ((u >> 16) & 1u);   // round-to-nearest-even
  return (unsigned short)(u >> 16);
}

__device__ __forceinline__ float sigm(float x) {
  return __builtin_amdgcn_rcpf(1.0f + __builtin_amdgcn_exp2f(-1.44269504f * x));
}
__device__ __forceinline__ float tanh_f(float x) {
  return 2.0f * __builtin_amdgcn_rcpf(1.0f + __builtin_amdgcn_exp2f(-2.88539008f * x)) - 1.0f;
}

// K1: weights prep + per-block pos histogram (no global atomics, no memset).
__global__ void prep_wt(const float* __restrict__ Wf, const float* __restrict__ Wiou,
                        unsigned short* __restrict__ wt,
                        const int* __restrict__ posp, int* __restrict__ hist2,
                        int N, int nhb) {
  int b = blockIdx.x, t = threadIdx.x;
  if (b < NPOS * 16) {
    __shared__ float tile[32][33];
    int p = b >> 4, jt = (b >> 2) & 3, kt = b & 3;
    int tx = t & 31, ty = t >> 5;            // 32 x 8
    #pragma unroll
    for (int it = 0; it < 4; ++it) {
      int krow = kt * 32 + ty + it * 8;
      int j = jt * 32 + tx;
      tile[ty + it * 8][tx] = Wf[(size_t)(p * H + krow) * H + j];
    }
    __syncthreads();
    #pragma unroll
    for (int it = 0; it < 4; ++it) {
      int j2 = jt * 32 + ty + it * 8;
      int k2 = kt * 32 + tx;
      wt[(size_t)p * 512 * H + (size_t)j2 * H + k2] = f2bf(tile[tx][ty + it * 8]);
    }
  } else if (b < NPOS * 16 + (NPOS * 384 * H) / 256) {
    int id = (b - NPOS * 16) * 256 + t;
    int p = id / 49152;
    int r = id - p * 49152;
    int k = r & 127;
    float v = Wiou[(size_t)(r >> 7) * (NPOS * H) + p * H + k];
    wt[(size_t)p * 65536 + 16384 + r] = f2bf(v);
  } else {
    int hb = b - (NPOS * 16 + (NPOS * 384 * H) / 256);
    __shared__ int c[NPOS];
    if (t < NPOS) c[t] = 0;
    __syncthreads();
    int i = hb * 256 + t;
    if (i < N) atomicAdd(&c[posp[i]], 1);    // LDS atomic only
    __syncthreads();
    if (t < NPOS) hist2[hb * 16 + t] = c[t];
  }
}

// K2: wave-parallel scans. 640 threads = 10 waves; wave w owns pos w.
// off2[b][p] = global scatter base for hist-block b, pos p. Also block table.
__global__ void scan_build(const int* __restrict__ hist2, int nhb,
                           int* __restrict__ off2,
                           int* __restrict__ blkpos, int* __restrict__ blkgs,
                           int* __restrict__ blkcnt, int maxb) {
  __shared__ int tot[NPOS], base[NPOS + 1], bb[NPOS + 1];
  int t = threadIdx.x;
  int w = t >> 6, l = t & 63;
  if (w < NPOS) {
    int b0 = 2 * l, b1 = 2 * l + 1;
    int a  = (b0 < nhb) ? hist2[b0 * 16 + w] : 0;
    int bv = (b1 < nhb) ? hist2[b1 * 16 + w] : 0;
    int s = a + bv, sc = s;
    #pragma unroll
    for (int off = 1; off < 64; off <<= 1) {
      int u = __shfl_up(sc, off);
      if (l >= off) sc += u;
    }
    int excl = sc - s;                       // exclusive prefix of pair-sums
    if (b0 < nhb) off2[b0 * 16 + w] = excl;
    if (b1 < nhb) off2[b1 * 16 + w] = excl + a;
    if (l == 63) tot[w] = sc;
  }
  __syncthreads();
  if (t == 0) {
    int run = 0, rb = 0;
    for (int p = 0; p < NPOS; ++p) {
      base[p] = run; bb[p] = rb;
      run += tot[p];
      rb += (tot[p] + ROWSB - 1) / ROWSB;
    }
    base[NPOS] = run; bb[NPOS] = rb;
  }
  __syncthreads();
  for (int i = t; i < nhb * NPOS; i += 640) {
    int b = i / NPOS, p = i - b * NPOS;
    off2[b * 16 + p] += base[p];
  }
  int nb = bb[NPOS];
  for (int b = t; b < maxb; b += 640) {
    if (b < nb) {
      int p = 0;
      while (bb[p + 1] <= b) ++p;
      int s = (b - bb[p]) * ROWSB;
      blkpos[b] = p;
      blkgs[b] = base[p] + s;
      blkcnt[b] = min(ROWSB, tot[p] - s);
    } else {
      blkpos[b] = -1;
    }
  }
}

// K3: scatter, global-atomic-free.
// order entry packs: g (bits 0..15) | mask<<16 | (depth==1)<<17 | (depth==2)<<18
__global__ void scatter_idx(const int* __restrict__ posp, const int* __restrict__ depthp,
                            const int* __restrict__ maskp, const int* __restrict__ off2,
                            unsigned* __restrict__ order, int N) {
  __shared__ int c[NPOS], basearr[NPOS];
  int hb = blockIdx.x, t = threadIdx.x;
  if (t < NPOS) { c[t] = 0; basearr[t] = off2[hb * 16 + t]; }
  __syncthreads();
  int i = hb * 256 + t;
  int p = -1, r = 0;
  unsigned e = 0;
  if (i < N) {
    p = posp[i];
    r = atomicAdd(&c[p], 1);                 // LDS atomic only
    int d = depthp[i];
    int mk = maskp[i];
    e = (unsigned)i | ((unsigned)mk << 16) |
        ((unsigned)(d == 1) << 17) | ((unsigned)(d == 2) << 18);
  }
  __syncthreads();
  if (p >= 0) order[basearr[p] + r] = e;
}

__global__ __launch_bounds__(BLOCK, 3) void tree_lstm_main(
    const float* __restrict__ child_h, const float* __restrict__ child_c,
    const float* __restrict__ e1, const float* __restrict__ e2,
    const float* __restrict__ h_prev,
    const float* __restrict__ b_f, const float* __restrict__ b_iou,
    const unsigned short* __restrict__ wt,
    const unsigned* __restrict__ order, const int* __restrict__ blkpos,
    const int* __restrict__ blkgs, const int* __restrict__ blkcnt,
    float* __restrict__ out, int N) {

  const int b = blockIdx.x;
  const int p = blkpos[b];
  if (p < 0) return;
  const int gs = blkgs[b], cnth = blkcnt[b];

  __shared__ unsigned short hs[ROWSB * H];   // 8 KB, XOR-swizzled bf16 h_cat
  __shared__ unsigned rowg[ROWSB];

  const int t = threadIdx.x;
  const int wv = t >> 6, l = t & 63;
  const int l15 = l & 15, lhi = l >> 4;
  const int colr = wv * 16 + l15;            // wave's output column 0..127
  const int kof = lhi * 8;

  const unsigned short* wb0 = wt + (size_t)p * 512 * H + (size_t)colr * H + kof;

  if (t < ROWSB) rowg[t] = (t < cnth) ? order[gs + t] : 0xFFFFFFFFu;
  __syncthreads();

  // ---- stage A: 32 rows x 128 bf16 (child_h + depth-class extras) ----
  {
    int id = t;
    int row = id >> 4, c8 = id & 15;
    unsigned e = rowg[row];
    float4 a0 = {0.f, 0.f, 0.f, 0.f}, a1 = {0.f, 0.f, 0.f, 0.f};
    if ((int)e >= 0) {
      int g = e & 0xFFFF;
      const float4* ph = (const float4*)(child_h + (size_t)g * H + c8 * 8);
      a0 = ph[0]; a1 = ph[1];
      if (e & (3u << 17)) {
        const float* ep = (e & (1u << 17)) ? e1 : e2;
        const float4* pe = (const float4*)(ep + (size_t)g * H + c8 * 8);
        float4 b0 = pe[0], b1 = pe[1];
        a0.x += b0.x; a0.y += b0.y; a0.z += b0.z; a0.w += b0.w;
        a1.x += b1.x; a1.y += b1.y; a1.z += b1.z; a1.w += b1.w;
      }
    }
    bf16x8 v;
    v[0] = (short)f2bf(a0.x); v[1] = (short)f2bf(a0.y);
    v[2] = (short)f2bf(a0.z); v[3] = (short)f2bf(a0.w);
    v[4] = (short)f2bf(a1.x); v[5] = (short)f2bf(a1.y);
    v[6] = (short)f2bf(a1.z); v[7] = (short)f2bf(a1.w);
    int wb = (row * 256 + c8 * 16) ^ ((row & 7) << 4);
    *(bf16x8*)((char*)hs + wb) = v;
  }
  __syncthreads();

  const size_t NH = (size_t)N * H;
  const float bfv = b_f[p * H + colr];
  const float b_i = b_iou[colr], b_o = b_iou[H + colr], b_g = b_iou[2 * H + colr];

  const int nchunk = (cnth + 15) >> 4;
  for (int c = 0; c < nchunk; ++c) {
    const int r0 = c * 16;

    // ---- B panel FIRST: oldest outstanding loads -> MFMA waits only these
    //      (vmcnt drains in issue order; gathers must be younger than B) ----
    bf16x8 Bu[4], Biq[4], Boq[4], Bgq[4];
    #pragma unroll
    for (int kk = 0; kk < 4; ++kk) {
      Bu[kk]  = *(const bf16x8*)(wb0 + kk * 32);
      Biq[kk] = *(const bf16x8*)(wb0 + 128 * H + kk * 32);
      Boq[kk] = *(const bf16x8*)(wb0 + 256 * H + kk * 32);
      Bgq[kk] = *(const bf16x8*)(wb0 + 384 * H + kk * 32);
    }
    __builtin_amdgcn_sched_barrier(0);

    // ---- epilogue gathers (younger; land under MFMA, drained by epilogue) ----
    unsigned gg[4]; float cc[4], hpv[4];
    #pragma unroll
    for (int q = 0; q < 4; ++q) {
      int rr = r0 + lhi * 4 + q;
      gg[q] = (rr < cnth) ? rowg[rr] : 0xFFFFFFFFu;
    }
    #pragma unroll
    for (int q = 0; q < 4; ++q) {
      if ((int)gg[q] >= 0) {
        size_t gi = (size_t)(gg[q] & 0xFFFF) * H + colr;
        cc[q] = child_c[gi];
        hpv[q] = h_prev[gi];
      } else { cc[q] = 0.f; hpv[q] = 0.f; }
    }
    __builtin_amdgcn_sched_barrier(0);

    // ---- A fragments from LDS (lgkm counter, independent of vmcnt) ----
    const int arow = r0 + l15;
    bf16x8 afr[4];
    #pragma unroll
    for (int kk = 0; kk < 4; ++kk) {
      int rb = (arow * 256 + kk * 64 + lhi * 16) ^ ((arow & 7) << 4);
      afr[kk] = *(const bf16x8*)((const char*)hs + rb);
    }

    f32x4 au = {0.f, 0.f, 0.f, 0.f};
    f32x4 ai = {0.f, 0.f, 0.f, 0.f};
    f32x4 ao = {0.f, 0.f, 0.f, 0.f};
    f32x4 ag = {0.f, 0.f, 0.f, 0.f};
    #pragma unroll
    for (int kk = 0; kk < 4; ++kk) {
      au = __builtin_amdgcn_mfma_f32_16x16x32_bf16(afr[kk], Bu[kk],  au, 0, 0, 0);
      ai = __builtin_amdgcn_mfma_f32_16x16x32_bf16(afr[kk], Biq[kk], ai, 0, 0, 0);
      ao = __builtin_amdgcn_mfma_f32_16x16x32_bf16(afr[kk], Boq[kk], ao, 0, 0, 0);
      ag = __builtin_amdgcn_mfma_f32_16x16x32_bf16(afr[kk], Bgq[kk], ag, 0, 0, 0);
    }

    // epilogue: D row = (l>>4)*4 + q, col = l&15 (verified mapping)
    #pragma unroll
    for (int q = 0; q < 4; ++q) {
      if ((int)gg[q] >= 0) {
        size_t gi = (size_t)(gg[q] & 0xFFFF) * H + colr;
        float u = au[q] + bfv;
        float iv = ai[q] + b_i;
        float ov = ao[q] + b_o;
        float gv = ag[q] + b_g;
        float f = sigm(u);
        float credv = f * cc[q];
        float cnew = sigm(iv) * tanh_f(gv) + credv;
        float hnew = sigm(ov) * tanh_f(cnew);
        float m = (float)((gg[q] >> 16) & 1u);
        float hv = hpv[q] * m + (1.0f - m) * hnew;
        float cv = credv * m + (1.0f - m) * cnew;
        out[gi] = hv;
        out[NH + gi] = cv;
      }
    }
  }
}

extern "C" void kernel_launch(void* const* d_in, const int* in_sizes, int n_in,
                              void* d_out, int out_size, void* d_ws, size_t ws_size,
                              hipStream_t stream) {
  const float* child_h = (const float*)d_in[0];
  const float* child_c = (const float*)d_in[1];
  const float* e1      = (const float*)d_in[2];
  const float* e2      = (const float*)d_in[3];
  const float* h_prev  = (const float*)d_in[4];
  const int*   posp    = (const int*)d_in[5];
  const int*   depthp  = (const int*)d_in[6];
  const int*   maskp   = (const int*)d_in[7];
  const float* W_f     = (const float*)d_in[8];
  const float* b_f     = (const float*)d_in[9];
  const float* W_iou   = (const float*)d_in[10];
  const float* b_iou   = (const float*)d_in[11];
  float* out = (float*)d_out;
  int N = in_sizes[0] / H;
  int nhb = (N + 255) / 256;                 // histogram/scatter blocks
  int maxb = NPOS + N / ROWSB;

  // ws layout
  unsigned short* wt = (unsigned short*)d_ws;          // 655360 * 2B
  int* hist2  = (int*)((char*)d_ws + (size_t)NPOS * 512 * H * 2);  // nhb*16
  int* off2   = hist2 + nhb * 16;                                   // nhb*16
  int* blkpos = off2 + nhb * 16;
  int* blkgs  = blkpos + maxb;
  int* blkcnt = blkgs + maxb;
  unsigned* order = (unsigned*)(blkcnt + maxb);

  int prep_blocks = NPOS * 16 + (NPOS * 384 * H) / 256 + nhb;
  hipLaunchKernelGGL(prep_wt, dim3(prep_blocks), dim3(256), 0, stream,
                     W_f, W_iou, wt, posp, hist2, N, nhb);
  hipLaunchKernelGGL(scan_build, dim3(1), dim3(640), 0, stream,
                     hist2, nhb, off2, blkpos, blkgs, blkcnt, maxb);
  hipLaunchKernelGGL(scatter_idx, dim3(nhb), dim3(256), 0, stream,
                     posp, depthp, maskp, off2, order, N);
  hipLaunchKernelGGL(tree_lstm_main, dim3(maxb), dim3(BLOCK), 0, stream,
                     child_h, child_c, e1, e2, h_prev,
                     b_f, b_iou, wt, order, blkpos, blkgs, blkcnt, out, N);
}